// Round 1
// baseline (379.585 us; speedup 1.0000x reference)
//
#include <hip/hip_runtime.h>

// Problem constants (from reference): B=8, N=256, D=128
constexpr int Bc = 8;
constexpr int Nc = 256;
constexpr int Dc = 128;

// ---------------------------------------------------------------------------
// Kernel 1: per-node projections  Ux = x@Wu + bu,  Vx = x@Wv + bv
// Grid: (B*N)/ROWS blocks of 512 threads. Thread = (column t in [0,128),
// row-group rr in [0,4)). Wu/Wv (64 KiB each) stay L2-resident; x row is
// staged in LDS and read via bank-broadcast.
// ---------------------------------------------------------------------------
__global__ __launch_bounds__(512) void proj_kernel(
    const float* __restrict__ x,
    const float* __restrict__ Wu, const float* __restrict__ bu,
    const float* __restrict__ Wv, const float* __restrict__ bv,
    float* __restrict__ Ux, float* __restrict__ Vx)
{
    constexpr int ROWS = 4;
    __shared__ float xs[ROWS][Dc];
    const int t   = threadIdx.x & 127;   // output column
    const int rr  = threadIdx.x >> 7;    // row within block
    const int row = blockIdx.x * ROWS + rr;

    xs[rr][t] = x[row * Dc + t];
    __syncthreads();

    float accu = bu[t];
    float accv = bv[t];
    #pragma unroll 8
    for (int k = 0; k < Dc; ++k) {
        const float xk = xs[rr][k];          // LDS broadcast (conflict-free)
        accu = fmaf(xk, Wu[k * Dc + t], accu);  // coalesced, L2-hit
        accv = fmaf(xk, Wv[k * Dc + t], accv);
    }
    Ux[row * Dc + t] = accu;
    Vx[row * Dc + t] = accv;
}

// ---------------------------------------------------------------------------
// Kernel 2: fused  out[b,i,d] = Ux[b,i,d] + (sum_j g[b,i,j,d]*Vx[b,j,d])
//                                           / (1e-20 + sum_j g[b,i,j,d])
// ONE pass over the 256 MiB edge_gate tensor (both reductions fused).
// Grid: B*N blocks of 256 threads. tid = d4 (32 float4 lanes over D=128)
//                                  + 32*jj (8-way parallelism over j).
// Each thread register-accumulates its j-strided slice; 8-way LDS reduce.
// ---------------------------------------------------------------------------
__global__ __launch_bounds__(256) void gate_kernel(
    const float* __restrict__ gate,
    const float* __restrict__ Ux, const float* __restrict__ Vx,
    float* __restrict__ out)
{
    const int bi  = blockIdx.x;          // b*N + i
    const int b   = bi >> 8;             // N = 256
    const int tid = threadIdx.x;
    const int d4  = tid & 31;            // float4 index over D
    const int jj  = tid >> 5;            // 0..7

    const float4* gptr = reinterpret_cast<const float4*>(gate)
                       + (size_t)bi * (Nc * Dc / 4) + d4;
    const float4* vptr = reinterpret_cast<const float4*>(Vx)
                       + b * (Nc * Dc / 4) + d4;

    float4 sgv = make_float4(0.f, 0.f, 0.f, 0.f);  // sum gate * Vx
    float4 sg  = make_float4(0.f, 0.f, 0.f, 0.f);  // sum gate

    #pragma unroll 4
    for (int j = jj; j < Nc; j += 8) {
        const float4 g = gptr[j * (Dc / 4)];   // HBM, coalesced 512B segments
        const float4 v = vptr[j * (Dc / 4)];   // L2-resident (128 KiB/batch)
        sgv.x = fmaf(g.x, v.x, sgv.x);
        sgv.y = fmaf(g.y, v.y, sgv.y);
        sgv.z = fmaf(g.z, v.z, sgv.z);
        sgv.w = fmaf(g.w, v.w, sgv.w);
        sg.x += g.x; sg.y += g.y; sg.z += g.z; sg.w += g.w;
    }

    __shared__ float4 s_gv[256];
    __shared__ float4 s_g[256];
    s_gv[tid] = sgv;
    s_g[tid]  = sg;
    __syncthreads();

    if (jj == 0) {
        #pragma unroll
        for (int k = 1; k < 8; ++k) {
            const float4 a = s_gv[d4 + 32 * k];
            const float4 c = s_g [d4 + 32 * k];
            sgv.x += a.x; sgv.y += a.y; sgv.z += a.z; sgv.w += a.w;
            sg.x  += c.x; sg.y  += c.y; sg.z  += c.z; sg.w  += c.w;
        }
        const float4 u = reinterpret_cast<const float4*>(Ux)[bi * (Dc / 4) + d4];
        float4 r;
        r.x = u.x + sgv.x / (1e-20f + sg.x);
        r.y = u.y + sgv.y / (1e-20f + sg.y);
        r.z = u.z + sgv.z / (1e-20f + sg.z);
        r.w = u.w + sgv.w / (1e-20f + sg.w);
        reinterpret_cast<float4*>(out)[bi * (Dc / 4) + d4] = r;
    }
}

extern "C" void kernel_launch(void* const* d_in, const int* in_sizes, int n_in,
                              void* d_out, int out_size, void* d_ws, size_t ws_size,
                              hipStream_t stream)
{
    const float* x    = (const float*)d_in[0];
    const float* gate = (const float*)d_in[1];
    const float* Wu   = (const float*)d_in[2];
    const float* bu   = (const float*)d_in[3];
    const float* Wv   = (const float*)d_in[4];
    const float* bv   = (const float*)d_in[5];
    float* out = (float*)d_out;

    float* Ux = (float*)d_ws;                 // B*N*D floats = 1 MiB
    float* Vx = Ux + Bc * Nc * Dc;            // next 1 MiB

    proj_kernel<<<(Bc * Nc) / 4, 512, 0, stream>>>(x, Wu, bu, Wv, bv, Ux, Vx);
    gate_kernel<<<Bc * Nc, 256, 0, stream>>>(gate, Ux, Vx, out);
}

// Round 7
// 362.283 us; speedup vs baseline: 1.0478x; 1.0478x over previous
//
#include <hip/hip_runtime.h>

// Problem constants (from reference): B=8, N=256, D=128
constexpr int Bc = 8;
constexpr int Nc = 256;
constexpr int Dc = 128;

typedef float floatx4 __attribute__((ext_vector_type(4)));  // native vec for nontemporal builtin

// ---------------------------------------------------------------------------
// Kernel 1: per-node projections  Ux = x@Wu + bu,  Vx = x@Wv + bv
// Grid: (B*N)/4 blocks x 512 threads. Thread = (column t, row-group rr).
// Wu/Wv (64 KiB each) are L2-resident; x row staged in LDS (bank-broadcast).
// ~2-5 us total, not the bottleneck.
// ---------------------------------------------------------------------------
__global__ __launch_bounds__(512) void proj_kernel(
    const float* __restrict__ x,
    const float* __restrict__ Wu, const float* __restrict__ bu,
    const float* __restrict__ Wv, const float* __restrict__ bv,
    float* __restrict__ Ux, float* __restrict__ Vx)
{
    constexpr int ROWS = 4;
    __shared__ float xs[ROWS][Dc];
    const int t   = threadIdx.x & 127;   // output column
    const int rr  = threadIdx.x >> 7;    // row within block
    const int row = blockIdx.x * ROWS + rr;

    xs[rr][t] = x[row * Dc + t];
    __syncthreads();

    float accu = bu[t];
    float accv = bv[t];
    #pragma unroll 8
    for (int k = 0; k < Dc; ++k) {
        const float xk = xs[rr][k];             // LDS broadcast (conflict-free)
        accu = fmaf(xk, Wu[k * Dc + t], accu);  // coalesced, L2-hit
        accv = fmaf(xk, Wv[k * Dc + t], accv);
    }
    Ux[row * Dc + t] = accu;
    Vx[row * Dc + t] = accv;
}

// ---------------------------------------------------------------------------
// Kernel 2: fused  out[b,i,d] = Ux[b,i,d] + (sum_j g[b,i,j,d]*Vx[b,j,d])
//                                           / (1e-20 + sum_j g[b,i,j,d])
// ONE pass over the 256 MiB edge_gate tensor (both reductions fused).
// Grid: B*N blocks x 256 threads. tid = d4 (32 float4 lanes over D=128)
//                                 + 32*jj (8-way parallelism over j).
// gate loads are NONTEMPORAL (evict-first): the 256 MiB stream must not
// thrash the 1 MiB Vx working set out of L2.
// ---------------------------------------------------------------------------
__global__ __launch_bounds__(256) void gate_kernel(
    const float* __restrict__ gate,
    const float* __restrict__ Ux, const float* __restrict__ Vx,
    float* __restrict__ out)
{
    const int bi  = blockIdx.x;          // b*N + i
    const int b   = bi >> 8;             // N = 256
    const int tid = threadIdx.x;
    const int d4  = tid & 31;            // float4 index over D
    const int jj  = tid >> 5;            // 0..7

    const floatx4* gptr = reinterpret_cast<const floatx4*>(gate)
                        + (size_t)bi * (Nc * Dc / 4) + d4;
    const float4* vptr = reinterpret_cast<const float4*>(Vx)
                       + b * (Nc * Dc / 4) + d4;

    float4 sgv = make_float4(0.f, 0.f, 0.f, 0.f);  // sum gate * Vx
    float4 sg  = make_float4(0.f, 0.f, 0.f, 0.f);  // sum gate

    #pragma unroll 8
    for (int j = jj; j < Nc; j += 8) {
        const floatx4 g = __builtin_nontemporal_load(&gptr[j * (Dc / 4)]); // HBM stream, evict-first
        const float4 v = vptr[j * (Dc / 4)];                               // L2-resident (1 MiB total)
        sgv.x = fmaf(g.x, v.x, sgv.x);
        sgv.y = fmaf(g.y, v.y, sgv.y);
        sgv.z = fmaf(g.z, v.z, sgv.z);
        sgv.w = fmaf(g.w, v.w, sgv.w);
        sg.x += g.x; sg.y += g.y; sg.z += g.z; sg.w += g.w;
    }

    __shared__ float4 s_gv[256];
    __shared__ float4 s_g[256];
    s_gv[tid] = sgv;
    s_g[tid]  = sg;
    __syncthreads();

    if (jj == 0) {
        #pragma unroll
        for (int k = 1; k < 8; ++k) {
            const float4 a = s_gv[d4 + 32 * k];
            const float4 c = s_g [d4 + 32 * k];
            sgv.x += a.x; sgv.y += a.y; sgv.z += a.z; sgv.w += a.w;
            sg.x  += c.x; sg.y  += c.y; sg.z  += c.z; sg.w  += c.w;
        }
        const float4 u = reinterpret_cast<const float4*>(Ux)[bi * (Dc / 4) + d4];
        float4 r;
        r.x = u.x + sgv.x / (1e-20f + sg.x);
        r.y = u.y + sgv.y / (1e-20f + sg.y);
        r.z = u.z + sgv.z / (1e-20f + sg.z);
        r.w = u.w + sgv.w / (1e-20f + sg.w);
        reinterpret_cast<float4*>(out)[bi * (Dc / 4) + d4] = r;
    }
}

extern "C" void kernel_launch(void* const* d_in, const int* in_sizes, int n_in,
                              void* d_out, int out_size, void* d_ws, size_t ws_size,
                              hipStream_t stream)
{
    const float* x    = (const float*)d_in[0];
    const float* gate = (const float*)d_in[1];
    const float* Wu   = (const float*)d_in[2];
    const float* bu   = (const float*)d_in[3];
    const float* Wv   = (const float*)d_in[4];
    const float* bv   = (const float*)d_in[5];
    float* out = (float*)d_out;

    float* Ux = (float*)d_ws;                 // B*N*D floats = 1 MiB
    float* Vx = Ux + Bc * Nc * Dc;            // next 1 MiB

    proj_kernel<<<(Bc * Nc) / 4, 512, 0, stream>>>(x, Wu, bu, Wv, bv, Ux, Vx);
    gate_kernel<<<Bc * Nc, 256, 0, stream>>>(gate, Ux, Vx, out);
}